// Round 8
// baseline (480.683 us; speedup 1.0000x reference)
//
#include <hip/hip_runtime.h>
#include <stdint.h>

typedef unsigned short u16;
typedef u16   u16x4  __attribute__((ext_vector_type(4)));
typedef u16   u16x8  __attribute__((ext_vector_type(8)));
typedef __bf16 bf16x8 __attribute__((ext_vector_type(8)));
typedef float f32x4  __attribute__((ext_vector_type(4)));

static __device__ __forceinline__ u16 f32_bf16(float f) {
    uint32_t u = __builtin_bit_cast(uint32_t, f);
    u += 0x7fffu + ((u >> 16) & 1u);          // round-to-nearest-even
    return (u16)(u >> 16);
}
static __device__ __forceinline__ u16x8 cvt8(f32x4 a, f32x4 b) {
    u16x8 v;
#pragma unroll
    for (int e = 0; e < 4; ++e) { v[e] = f32_bf16(a[e]); v[4 + e] = f32_bf16(b[e]); }
    return v;
}

// ---------------------------------------------------------------------------
// 0. dtype detect (verified R5-R7): flag=1 -> fp32 inputs AND fp32 output.
// ---------------------------------------------------------------------------
__global__ __launch_bounds__(256) void detect_k(const u16* __restrict__ X, uint32_t* flag) {
    __shared__ int cnt[256];
    int t = threadIdx.x;
    int c = 0;
#pragma unroll
    for (int i = 0; i < 4; ++i) {
        u16 v = X[t + 256 * i];
        int e = (v >> 7) & 0xFF;
        c += (e >= 0xC2) ? 1 : 0;
    }
    cnt[t] = c;
    __syncthreads();
    for (int s = 128; s > 0; s >>= 1) {
        if (t < s) cnt[t] += cnt[t + s];
        __syncthreads();
    }
    if (t == 0) *flag = (cnt[0] > 32) ? 1u : 0u;
}

// ---------------------------------------------------------------------------
// 0b. X pre-convert to bf16 (identity copy when flag=0). Removes per-k-iter
//     fp32->bf16 VALU from the projection GEMM inner loops.
// ---------------------------------------------------------------------------
struct XJob { const void* in; u16* out; int n; };

__global__ __launch_bounds__(256) void convert_x(XJob j0, XJob j1, const uint32_t* __restrict__ flag) {
    const XJob job = (blockIdx.y == 0) ? j0 : j1;
    const bool f32in = (*flag != 0u);
    const int stride = gridDim.x * 256 * 8;
    for (int i = ((int)blockIdx.x * 256 + (int)threadIdx.x) * 8; i < job.n; i += stride) {
        u16x8 v;
        if (f32in) {
            const float* p = (const float*)job.in + i;
            v = cvt8(*(const f32x4*)p, *(const f32x4*)(p + 4));
        } else {
            v = *(const u16x8*)((const u16*)job.in + i);
        }
        *(u16x8*)(job.out + i) = v;
    }
}

// ---------------------------------------------------------------------------
// 1. Weight convert+transpose: Wt[n][k] = bf16(W[k][n]), 1024x1024, batched.
// ---------------------------------------------------------------------------
struct WJob { const void* in; u16* out; };
struct WBatch { WJob j[3]; };

__global__ __launch_bounds__(256) void convert_w(WBatch args, const uint32_t* __restrict__ flag) {
    __shared__ u16 tile[64][72];
    const bool f32in = (*flag != 0u);
    const void* in = args.j[blockIdx.z].in;
    u16*       out = args.j[blockIdx.z].out;
    const int t  = threadIdx.x;
    const int r0 = blockIdx.y * 64, c0 = blockIdx.x * 64;
    const int lr = t >> 3, lc = (t & 7) * 8;
#pragma unroll
    for (int pass = 0; pass < 2; ++pass) {
        int r = lr + pass * 32;
        u16x8 v;
        if (f32in) {
            const float* p = (const float*)in + (size_t)(r0 + r) * 1024 + c0 + lc;
            v = cvt8(*(const f32x4*)p, *(const f32x4*)(p + 4));
        } else {
            v = *(const u16x8*)((const u16*)in + (size_t)(r0 + r) * 1024 + c0 + lc);
        }
#pragma unroll
        for (int e = 0; e < 8; ++e) tile[r][lc + e] = v[e];
    }
    __syncthreads();
#pragma unroll
    for (int pass = 0; pass < 2; ++pass) {
        int n = lr + pass * 32;
        u16x8 v;
#pragma unroll
        for (int e = 0; e < 8; ++e) v[e] = tile[lc + e][n];
        *(u16x8*)(out + (size_t)(c0 + n) * 1024 + r0 + lc) = v;
    }
}

// ---------------------------------------------------------------------------
// 2. MFMA GEMM (verified R6/R7), A always bf16 now. vtNk>0 -> transposed
//    VT[h][d][key] epilogue; cF32able&&flag -> fp32 C at cOffElems.
// ---------------------------------------------------------------------------
struct GemmJob  { const u16* A; const u16* Bt; void* C; int M; int cF32able; int cOffElems; int vtNk; };
struct GemmBatch { GemmJob j[3]; };

__global__ __launch_bounds__(256) void gemm_bt(GemmBatch b, const uint32_t* __restrict__ flag) {
    const GemmJob job = b.j[blockIdx.z];
    const int K = 1024, N = 1024;
    const int m0 = blockIdx.y * 128;
    if (m0 >= job.M) return;
    const int n0 = blockIdx.x * 128;
    const bool cF = job.cF32able && (*flag != 0u);

    __shared__ u16 As[128 * 32];
    __shared__ u16 Bs[128 * 32];

    const int tid  = threadIdx.x;
    const int lane = tid & 63, wave = tid >> 6;
    const int quad = lane >> 4, l16 = lane & 15;
    const int wrow = wave >> 1, wcol = wave & 1;

    f32x4 acc[4][4];
#pragma unroll
    for (int i = 0; i < 4; ++i)
#pragma unroll
        for (int j = 0; j < 4; ++j) acc[i][j] = (f32x4){0.f, 0.f, 0.f, 0.f};

    for (int k0 = 0; k0 < K; k0 += 32) {
        u16x8 va[2], vb[2];
#pragma unroll
        for (int i = 0; i < 2; ++i) {
            int id = tid + 256 * i;
            int row = id >> 2, slot = id & 3;
            int src = (slot ^ ((row >> 1) & 3)) * 8;
            va[i] = *(const u16x8*)(job.A  + (size_t)(m0 + row) * K + k0 + src);
            vb[i] = *(const u16x8*)(job.Bt + (size_t)(n0 + row) * K + k0 + src);
        }
        __syncthreads();
#pragma unroll
        for (int i = 0; i < 2; ++i) {
            int id = tid + 256 * i;
            int row = id >> 2, slot = id & 3;
            *(u16x8*)(As + row * 32 + slot * 8) = va[i];
            *(u16x8*)(Bs + row * 32 + slot * 8) = vb[i];
        }
        __syncthreads();

        bf16x8 af[4], bfb[4];
#pragma unroll
        for (int i = 0; i < 4; ++i) {
            int r  = wrow * 64 + i * 16 + l16;
            af[i]  = *(const bf16x8*)(As + r * 32 + ((quad ^ ((r >> 1) & 3)) * 8));
            int rn = wcol * 64 + i * 16 + l16;
            bfb[i] = *(const bf16x8*)(Bs + rn * 32 + ((quad ^ ((rn >> 1) & 3)) * 8));
        }
#pragma unroll
        for (int i = 0; i < 4; ++i)
#pragma unroll
            for (int j = 0; j < 4; ++j)
                acc[i][j] = __builtin_amdgcn_mfma_f32_16x16x32_bf16(af[i], bfb[j], acc[i][j], 0, 0, 0);
    }

    if (job.vtNk > 0) {
        u16* VT = (u16*)job.C;
        const int Nk2 = job.vtNk;
#pragma unroll
        for (int i = 0; i < 4; ++i)
#pragma unroll
            for (int j = 0; j < 4; ++j) {
                int n   = n0 + wcol * 64 + j * 16 + l16;
                int hh  = n >> 6, dd = n & 63;
                int key = m0 + wrow * 64 + i * 16 + quad * 4;
                u16x4 vv;
#pragma unroll
                for (int r = 0; r < 4; ++r) vv[r] = f32_bf16(acc[i][j][r]);
                *(u16x4*)(VT + (size_t)hh * 64 * Nk2 + (size_t)dd * Nk2 + key) = vv;
            }
    } else if (cF) {
        float* C = (float*)job.C + job.cOffElems;
#pragma unroll
        for (int i = 0; i < 4; ++i)
#pragma unroll
            for (int j = 0; j < 4; ++j)
#pragma unroll
                for (int r = 0; r < 4; ++r) {
                    int gr = m0 + wrow * 64 + i * 16 + quad * 4 + r;
                    int gc = n0 + wcol * 64 + j * 16 + l16;
                    C[(size_t)gr * N + gc] = acc[i][j][r];
                }
    } else {
        u16* C = (u16*)job.C + job.cOffElems;
#pragma unroll
        for (int i = 0; i < 4; ++i)
#pragma unroll
            for (int j = 0; j < 4; ++j)
#pragma unroll
                for (int r = 0; r < 4; ++r) {
                    int gr = m0 + wrow * 64 + i * 16 + quad * 4 + r;
                    int gc = n0 + wcol * 64 + j * 16 + l16;
                    C[(size_t)gr * N + gc] = f32_bf16(acc[i][j][r]);
                }
    }
}

// ---------------------------------------------------------------------------
// 3. Fused MFMA attention v3, BOTH directions in one dispatch (1280 blocks).
//    Block = 256 thr (4 waves) = (head, 64 q); wave = (qhalf, khalf).
//    K staged in LDS (unpadded 128x64, source-XOR chunk swizzle);
//    V read DIRECTLY from global VT[h][d][key] (coalesced, L2-served) — no
//    Vs tile, no V staging. LDS 26.9 KB -> 6 blocks/CU resident.
// ---------------------------------------------------------------------------
struct AttnDir { const u16* Q; const u16* K; const u16* VT; u16* ctxT; int Nq; int Nk; int nBlk; };

__global__ __launch_bounds__(256, 5) void attn_k(AttnDir d0, AttnDir d1) {
    const int D = 1024;
    int b = blockIdx.x;
    const AttnDir dd = (b < d0.nBlk) ? d0 : d1;
    if (blockIdx.x >= (unsigned)d0.nBlk) b -= d0.nBlk;
    const int h  = b & 15;               // h fastest -> same-head blocks spread = XCD round-robin per head
    const int q0 = (b >> 4) * 64;
    const int Nq = dd.Nq, Nk = dd.Nk;
    const u16* __restrict__ Qp  = dd.Q;
    const u16* __restrict__ Kp  = dd.K;
    const u16* __restrict__ VTp = dd.VT;

    const int tid  = threadIdx.x;
    const int lane = tid & 63, w = tid >> 6;
    const int quad = lane >> 4, l16 = lane & 15;
    const int qhalf = w & 1, khalf = w >> 1;
    const int halfN = Nk >> 1;

    __shared__ u16 Ks[128 * 64];      // unpadded; chunk c of row r holds logical chunk c^(r&7)
    __shared__ u16 Pb[4][1280];       // per-wave P [32 q][40], 2560 B each
    __shared__ float Lb[64];          // cross-khalf l partials

    bf16x8 aq[2][2];
#pragma unroll
    for (int ms = 0; ms < 2; ++ms)
#pragma unroll
        for (int kc = 0; kc < 2; ++kc) {
            int q = q0 + qhalf * 32 + ms * 16 + l16;
            aq[ms][kc] = *(const bf16x8*)(Qp + (size_t)q * D + h * 64 + kc * 32 + quad * 8);
        }

    f32x4 o[2][4];
#pragma unroll
    for (int ms = 0; ms < 2; ++ms)
#pragma unroll
        for (int nj = 0; nj < 4; ++nj) o[ms][nj] = (f32x4){0.f, 0.f, 0.f, 0.f};
    float rs[2][4] = {};
    const float sc = 0.125f;

    u16* P = Pb[w];
    const size_t vtBase = (size_t)h * 64 * Nk;

    for (int k0 = 0; k0 < halfN; k0 += 64) {
        __syncthreads();              // prev tile reads done
        // stage Ks: 1024 chunks of 16B; LDS dest linear, SOURCE chunk XOR-swizzled
#pragma unroll
        for (int j = 0; j < 4; ++j) {
            int c = tid + 256 * j;
            int row = c >> 3, slot = c & 7;
            int src = (slot ^ (row & 7)) * 8;
            int gkey = (row >> 6) * halfN + k0 + (row & 63);
            u16x8 v = *(const u16x8*)(Kp + (size_t)gkey * D + h * 64 + src);
            *(u16x8*)(Ks + row * 64 + slot * 8) = v;
        }
        __syncthreads();              // staged

#pragma unroll
        for (int sub = 0; sub < 2; ++sub) {
            f32x4 s[2][2];
#pragma unroll
            for (int ms = 0; ms < 2; ++ms)
#pragma unroll
                for (int kn = 0; kn < 2; ++kn) s[ms][kn] = (f32x4){0.f, 0.f, 0.f, 0.f};
#pragma unroll
            for (int kn = 0; kn < 2; ++kn)
#pragma unroll
                for (int kc = 0; kc < 2; ++kc) {
                    int keyr = khalf * 64 + sub * 32 + kn * 16 + l16;
                    int phys = ((kc * 4 + quad) ^ (keyr & 7)) * 8;
                    bf16x8 bk = *(const bf16x8*)(Ks + keyr * 64 + phys);
#pragma unroll
                    for (int ms = 0; ms < 2; ++ms)
                        s[ms][kn] = __builtin_amdgcn_mfma_f32_16x16x32_bf16(aq[ms][kc], bk, s[ms][kn], 0, 0, 0);
                }

#pragma unroll
            for (int ms = 0; ms < 2; ++ms)
#pragma unroll
                for (int kn = 0; kn < 2; ++kn) {
                    int key = kn * 16 + l16;
#pragma unroll
                    for (int r = 0; r < 4; ++r) {
                        float p = __expf(s[ms][kn][r] * sc);
                        rs[ms][r] += p;
                        int ql = ms * 16 + quad * 4 + r;
                        P[ql * 40 + key] = f32_bf16(p);
                    }
                }

            bf16x8 pa[2];
#pragma unroll
            for (int ms = 0; ms < 2; ++ms)
                pa[ms] = *(const bf16x8*)(P + (ms * 16 + l16) * 40 + quad * 8);

            const int gk = khalf * halfN + k0 + sub * 32;     // global key base of strip
#pragma unroll
            for (int nj = 0; nj < 4; ++nj) {
                int d = nj * 16 + l16;
                bf16x8 bv = *(const bf16x8*)(VTp + vtBase + (size_t)d * Nk + gk + quad * 8);
#pragma unroll
                for (int ms = 0; ms < 2; ++ms)
                    o[ms][nj] = __builtin_amdgcn_mfma_f32_16x16x32_bf16(pa[ms], bv, o[ms][nj], 0, 0, 0);
            }
        }
    }

    // reduce row-sums across the 16 key-lanes
#pragma unroll
    for (int ms = 0; ms < 2; ++ms)
#pragma unroll
        for (int r = 0; r < 4; ++r) {
            float v = rs[ms][r];
            v += __shfl_xor(v, 1, 64);
            v += __shfl_xor(v, 2, 64);
            v += __shfl_xor(v, 4, 64);
            v += __shfl_xor(v, 8, 64);
            rs[ms][r] = v;
        }

    // cross-khalf combine (additive: partials are unnormalized)
    __syncthreads();
    float* Cb = (float*)Ks;           // [64 q][64 d] fp32 = exactly Ks' 16 KB
    if (khalf == 1) {
#pragma unroll
        for (int ms = 0; ms < 2; ++ms)
#pragma unroll
            for (int nj = 0; nj < 4; ++nj)
#pragma unroll
                for (int r = 0; r < 4; ++r)
                    Cb[(qhalf * 32 + ms * 16 + quad * 4 + r) * 64 + nj * 16 + l16] = o[ms][nj][r];
        if (l16 == 0)
#pragma unroll
            for (int ms = 0; ms < 2; ++ms)
#pragma unroll
                for (int r = 0; r < 4; ++r)
                    Lb[qhalf * 32 + ms * 16 + quad * 4 + r] = rs[ms][r];
    }
    __syncthreads();
    if (khalf == 0) {
        float inv[2][4];
#pragma unroll
        for (int ms = 0; ms < 2; ++ms)
#pragma unroll
            for (int r = 0; r < 4; ++r)
                inv[ms][r] = 1.0f / (rs[ms][r] + Lb[qhalf * 32 + ms * 16 + quad * 4 + r]);

        u16* R = &Pb[w * 2][0];       // [64 d][40] u16 spans two Pb slots
#pragma unroll
        for (int ms = 0; ms < 2; ++ms)
#pragma unroll
            for (int nj = 0; nj < 4; ++nj)
#pragma unroll
                for (int r = 0; r < 4; ++r) {
                    int d  = nj * 16 + l16;
                    int ql = ms * 16 + quad * 4 + r;
                    float v = o[ms][nj][r] + Cb[(qhalf * 32 + ql) * 64 + nj * 16 + l16];
                    R[d * 40 + ql] = f32_bf16(v * inv[ms][r]);
                }
#pragma unroll
        for (int i = 0; i < 4; ++i) {
            int cid = lane + 64 * i;
            int d = cid >> 2, c = cid & 3;
            u16x8 v = *(const u16x8*)(R + d * 40 + c * 8);
            *(u16x8*)(dd.ctxT + (size_t)h * 64 * Nq + (size_t)d * Nq + q0 + qhalf * 32 + c * 8) = v;
        }
    }
}

// ---------------------------------------------------------------------------
// launch — ws peak 15M u16 + 64 = 30 MB (ws >= 44 MB proven by R2/R3 identity).
// d_out u16 staging: Q1s[0,3M) Qs[3M,5M) Xb[5M,7M) X1b[7M,10M) — all dead
// before the final fp32 GEMM overwrites d_out.
// ---------------------------------------------------------------------------
extern "C" void kernel_launch(void* const* d_in, const int* in_sizes, int n_in,
                              void* d_out, int out_size, void* d_ws, size_t ws_size,
                              hipStream_t stream) {
    u16* ws = (u16*)d_ws;
    uint32_t* flag = (uint32_t*)ws;
    u16* A = ws + 64;
    const size_t M1 = 1024ull * 1024;

    u16* W3   = A;              // [0,3M)  : weight transposes; later ctx1 (3M)
    u16* Kd1  = A + 3 * M1;     // [3M,5M) : X@WK natural
    u16* VT   = A + 5 * M1;     // [5M,7M) : VT[16][64][2048]; later WfcT (2M)
    u16* K1d  = A + 7 * M1;     // [7M,10M): X1@WK1 natural
    u16* VT1  = A + 10 * M1;    // [10M,13M): VT1[16][64][3072]
    u16* ctx2 = A + 13 * M1;    // [13M,15M): ctx2 (dir2 writes DURING fused attn)

    u16* outw = (u16*)d_out;
    u16* Q1s  = outw;           // [0,3M)  X1@WQ1 (bf16 scratch in d_out)
    u16* Qs   = outw + 3 * M1;  // [3M,5M) X@WQ
    u16* Xb   = outw + 5 * M1;  // [5M,7M)  X as bf16
    u16* X1b  = outw + 7 * M1;  // [7M,10M) X1 as bf16

    u16* ctx1 = W3;
    u16* WfcT = VT;

    // 0. dtype detect
    detect_k<<<dim3(1), dim3(256), 0, stream>>>((const u16*)d_in[0], flag);

    // 0b. X, X1 -> bf16
    XJob xj0 = {d_in[0], Xb,  2048 * 1024};
    XJob xj1 = {d_in[1], X1b, 3072 * 1024};
    convert_x<<<dim3(128, 2), dim3(256), 0, stream>>>(xj0, xj1, flag);

    // 1a. transpose+convert WQ, WK, WV
    WBatch w1;
    w1.j[0].in = d_in[2]; w1.j[0].out = W3;
    w1.j[1].in = d_in[3]; w1.j[1].out = W3 + M1;
    w1.j[2].in = d_in[4]; w1.j[2].out = W3 + 2 * M1;
    convert_w<<<dim3(16, 16, 3), dim3(256), 0, stream>>>(w1, flag);

    // 1b. projections from Xb: Q -> d_out scratch, K natural, V -> VT
    GemmBatch g1;
    g1.j[0] = (GemmJob){Xb, W3,          Qs,  2048, 0, 0, 0};
    g1.j[1] = (GemmJob){Xb, W3 + M1,     Kd1, 2048, 0, 0, 0};
    g1.j[2] = (GemmJob){Xb, W3 + 2 * M1, VT,  2048, 0, 0, 2048};
    gemm_bt<<<dim3(8, 16, 3), dim3(256), 0, stream>>>(g1, flag);

    // 2a. transpose+convert WQ1, WK1, WV1
    WBatch w2;
    w2.j[0].in = d_in[5]; w2.j[0].out = W3;
    w2.j[1].in = d_in[6]; w2.j[1].out = W3 + M1;
    w2.j[2].in = d_in[7]; w2.j[2].out = W3 + 2 * M1;
    convert_w<<<dim3(16, 16, 3), dim3(256), 0, stream>>>(w2, flag);

    // 2b. projections from X1b
    GemmBatch g2;
    g2.j[0] = (GemmJob){X1b, W3,          Q1s, 3072, 0, 0, 0};
    g2.j[1] = (GemmJob){X1b, W3 + M1,     K1d, 3072, 0, 0, 0};
    g2.j[2] = (GemmJob){X1b, W3 + 2 * M1, VT1, 3072, 0, 0, 3072};
    gemm_bt<<<dim3(8, 24, 3), dim3(256), 0, stream>>>(g2, flag);

    // 3. fused attention, both directions (dir1: 48*16=768 blocks; dir2: 512)
    AttnDir a0 = {Q1s, Kd1, VT,  ctx1, 3072, 2048, 768};
    AttnDir a1 = {Qs,  K1d, VT1, ctx2, 2048, 3072, 512};
    attn_k<<<dim3(1280), dim3(256), 0, stream>>>(a0, a1);

    // 4. transpose+convert Wfc, Wfc1 into dead VT region
    WBatch w3;
    w3.j[0].in = d_in[8]; w3.j[0].out = WfcT;
    w3.j[1].in = d_in[9]; w3.j[1].out = WfcT + M1;
    w3.j[2] = w3.j[0];
    convert_w<<<dim3(16, 16, 2), dim3(256), 0, stream>>>(w3, flag);

    // 5. output GEMMs into d_out (fp32 when flag; all d_out staging dead)
    GemmBatch g3;
    g3.j[0] = (GemmJob){ctx1, WfcT,      d_out, 3072, 1, 0,               0};
    g3.j[1] = (GemmJob){ctx2, WfcT + M1, d_out, 2048, 1, 3 * 1024 * 1024, 0};
    g3.j[2] = g3.j[0];
    gemm_bt<<<dim3(8, 24, 2), dim3(256), 0, stream>>>(g3, flag);
}

// Round 9
// 306.951 us; speedup vs baseline: 1.5660x; 1.5660x over previous
//
#include <hip/hip_runtime.h>
#include <stdint.h>

typedef unsigned short u16;
typedef u16   u16x4  __attribute__((ext_vector_type(4)));
typedef u16   u16x8  __attribute__((ext_vector_type(8)));
typedef __bf16 bf16x8 __attribute__((ext_vector_type(8)));
typedef float f32x4  __attribute__((ext_vector_type(4)));

static __device__ __forceinline__ u16 f32_bf16(float f) {
    uint32_t u = __builtin_bit_cast(uint32_t, f);
    u += 0x7fffu + ((u >> 16) & 1u);          // round-to-nearest-even
    return (u16)(u >> 16);
}
static __device__ __forceinline__ u16x8 cvt8(f32x4 a, f32x4 b) {
    u16x8 v;
#pragma unroll
    for (int e = 0; e < 4; ++e) { v[e] = f32_bf16(a[e]); v[4 + e] = f32_bf16(b[e]); }
    return v;
}

// ---------------------------------------------------------------------------
// 0. dtype detect (verified R5-R8): flag=1 -> fp32 inputs AND fp32 output.
// ---------------------------------------------------------------------------
__global__ __launch_bounds__(256) void detect_k(const u16* __restrict__ X, uint32_t* flag) {
    __shared__ int cnt[256];
    int t = threadIdx.x;
    int c = 0;
#pragma unroll
    for (int i = 0; i < 4; ++i) {
        u16 v = X[t + 256 * i];
        int e = (v >> 7) & 0xFF;
        c += (e >= 0xC2) ? 1 : 0;
    }
    cnt[t] = c;
    __syncthreads();
    for (int s = 128; s > 0; s >>= 1) {
        if (t < s) cnt[t] += cnt[t + s];
        __syncthreads();
    }
    if (t == 0) *flag = (cnt[0] > 32) ? 1u : 0u;
}

// ---------------------------------------------------------------------------
// 0b. X pre-convert to bf16 (identity copy when flag=0).
// ---------------------------------------------------------------------------
struct XJob { const void* in; u16* out; int n; };

__global__ __launch_bounds__(256) void convert_x(XJob j0, XJob j1, const uint32_t* __restrict__ flag) {
    const XJob job = (blockIdx.y == 0) ? j0 : j1;
    const bool f32in = (*flag != 0u);
    const int stride = gridDim.x * 256 * 8;
    for (int i = ((int)blockIdx.x * 256 + (int)threadIdx.x) * 8; i < job.n; i += stride) {
        u16x8 v;
        if (f32in) {
            const float* p = (const float*)job.in + i;
            v = cvt8(*(const f32x4*)p, *(const f32x4*)(p + 4));
        } else {
            v = *(const u16x8*)((const u16*)job.in + i);
        }
        *(u16x8*)(job.out + i) = v;
    }
}

// ---------------------------------------------------------------------------
// 1. Weight convert+transpose, all 8 matrices in one dispatch.
// ---------------------------------------------------------------------------
struct WJob { const void* in; u16* out; };
struct WBatch8 { WJob j[8]; };

__global__ __launch_bounds__(256) void convert_w(WBatch8 args, const uint32_t* __restrict__ flag) {
    __shared__ u16 tile[64][72];
    const bool f32in = (*flag != 0u);
    const void* in = args.j[blockIdx.z].in;
    u16*       out = args.j[blockIdx.z].out;
    const int t  = threadIdx.x;
    const int r0 = blockIdx.y * 64, c0 = blockIdx.x * 64;
    const int lr = t >> 3, lc = (t & 7) * 8;
#pragma unroll
    for (int pass = 0; pass < 2; ++pass) {
        int r = lr + pass * 32;
        u16x8 v;
        if (f32in) {
            const float* p = (const float*)in + (size_t)(r0 + r) * 1024 + c0 + lc;
            v = cvt8(*(const f32x4*)p, *(const f32x4*)(p + 4));
        } else {
            v = *(const u16x8*)((const u16*)in + (size_t)(r0 + r) * 1024 + c0 + lc);
        }
#pragma unroll
        for (int e = 0; e < 8; ++e) tile[r][lc + e] = v[e];
    }
    __syncthreads();
#pragma unroll
    for (int pass = 0; pass < 2; ++pass) {
        int n = lr + pass * 32;
        u16x8 v;
#pragma unroll
        for (int e = 0; e < 8; ++e) v[e] = tile[lc + e][n];
        *(u16x8*)(out + (size_t)(c0 + n) * 1024 + r0 + lc) = v;
    }
}

// ---------------------------------------------------------------------------
// 2. MFMA GEMM (verified R6-R8), A bf16. vtNk>0 -> transposed VT[h][d][key]
//    epilogue; cF32able&&flag -> fp32 C at cOffElems. 6 jobs per dispatch.
// ---------------------------------------------------------------------------
struct GemmJob  { const u16* A; const u16* Bt; void* C; int M; int cF32able; int cOffElems; int vtNk; };
struct GemmBatch6 { GemmJob j[6]; };

__global__ __launch_bounds__(256) void gemm_bt(GemmBatch6 b, const uint32_t* __restrict__ flag) {
    const GemmJob job = b.j[blockIdx.z];
    const int K = 1024, N = 1024;
    const int m0 = blockIdx.y * 128;
    if (m0 >= job.M) return;
    const int n0 = blockIdx.x * 128;
    const bool cF = job.cF32able && (*flag != 0u);

    __shared__ u16 As[128 * 32];
    __shared__ u16 Bs[128 * 32];

    const int tid  = threadIdx.x;
    const int lane = tid & 63, wave = tid >> 6;
    const int quad = lane >> 4, l16 = lane & 15;
    const int wrow = wave >> 1, wcol = wave & 1;

    f32x4 acc[4][4];
#pragma unroll
    for (int i = 0; i < 4; ++i)
#pragma unroll
        for (int j = 0; j < 4; ++j) acc[i][j] = (f32x4){0.f, 0.f, 0.f, 0.f};

    for (int k0 = 0; k0 < K; k0 += 32) {
        u16x8 va[2], vb[2];
#pragma unroll
        for (int i = 0; i < 2; ++i) {
            int id = tid + 256 * i;
            int row = id >> 2, slot = id & 3;
            int src = (slot ^ ((row >> 1) & 3)) * 8;
            va[i] = *(const u16x8*)(job.A  + (size_t)(m0 + row) * K + k0 + src);
            vb[i] = *(const u16x8*)(job.Bt + (size_t)(n0 + row) * K + k0 + src);
        }
        __syncthreads();
#pragma unroll
        for (int i = 0; i < 2; ++i) {
            int id = tid + 256 * i;
            int row = id >> 2, slot = id & 3;
            *(u16x8*)(As + row * 32 + slot * 8) = va[i];
            *(u16x8*)(Bs + row * 32 + slot * 8) = vb[i];
        }
        __syncthreads();

        bf16x8 af[4], bfb[4];
#pragma unroll
        for (int i = 0; i < 4; ++i) {
            int r  = wrow * 64 + i * 16 + l16;
            af[i]  = *(const bf16x8*)(As + r * 32 + ((quad ^ ((r >> 1) & 3)) * 8));
            int rn = wcol * 64 + i * 16 + l16;
            bfb[i] = *(const bf16x8*)(Bs + rn * 32 + ((quad ^ ((rn >> 1) & 3)) * 8));
        }
#pragma unroll
        for (int i = 0; i < 4; ++i)
#pragma unroll
            for (int j = 0; j < 4; ++j)
                acc[i][j] = __builtin_amdgcn_mfma_f32_16x16x32_bf16(af[i], bfb[j], acc[i][j], 0, 0, 0);
    }

    if (job.vtNk > 0) {
        u16* VT = (u16*)job.C;
        const int Nk2 = job.vtNk;
#pragma unroll
        for (int i = 0; i < 4; ++i)
#pragma unroll
            for (int j = 0; j < 4; ++j) {
                int n   = n0 + wcol * 64 + j * 16 + l16;
                int hh  = n >> 6, dd = n & 63;
                int key = m0 + wrow * 64 + i * 16 + quad * 4;
                u16x4 vv;
#pragma unroll
                for (int r = 0; r < 4; ++r) vv[r] = f32_bf16(acc[i][j][r]);
                *(u16x4*)(VT + (size_t)hh * 64 * Nk2 + (size_t)dd * Nk2 + key) = vv;
            }
    } else if (cF) {
        float* C = (float*)job.C + job.cOffElems;
#pragma unroll
        for (int i = 0; i < 4; ++i)
#pragma unroll
            for (int j = 0; j < 4; ++j)
#pragma unroll
                for (int r = 0; r < 4; ++r) {
                    int gr = m0 + wrow * 64 + i * 16 + quad * 4 + r;
                    int gc = n0 + wcol * 64 + j * 16 + l16;
                    C[(size_t)gr * N + gc] = acc[i][j][r];
                }
    } else {
        u16* C = (u16*)job.C + job.cOffElems;
#pragma unroll
        for (int i = 0; i < 4; ++i)
#pragma unroll
            for (int j = 0; j < 4; ++j)
#pragma unroll
                for (int r = 0; r < 4; ++r) {
                    int gr = m0 + wrow * 64 + i * 16 + quad * 4 + r;
                    int gc = n0 + wcol * 64 + j * 16 + l16;
                    C[(size_t)gr * N + gc] = f32_bf16(acc[i][j][r]);
                }
    }
}

// ---------------------------------------------------------------------------
// 3. Fused MFMA attention v4, both dirs, one dispatch (1280 blocks = 5/CU,
//    all resident). Block = 256 thr (4 waves) = (head, 64 q); wave =
//    (qhalf, khalf). Per iter: 64-key tile (32/khalf), K AND V staged in LDS
//    (XOR-swizzled chunks), register-prefetched one tile ahead so global
//    latency overlaps compute. LDS 26.9 KB -> 6 blocks/CU capacity.
// ---------------------------------------------------------------------------
struct AttnDir { const u16* Q; const u16* K; const u16* VT; u16* ctxT; int Nq; int Nk; int nBlk; };

__global__ __launch_bounds__(256, 5) void attn_k(AttnDir d0, AttnDir d1) {
    const int D = 1024;
    int b = blockIdx.x;
    const AttnDir dd = (b < d0.nBlk) ? d0 : d1;
    if (blockIdx.x >= (unsigned)d0.nBlk) b -= d0.nBlk;
    const int h  = b & 15;
    const int q0 = (b >> 4) * 64;
    const int Nq = dd.Nq, Nk = dd.Nk;
    const u16* __restrict__ Qp  = dd.Q;
    const u16* __restrict__ Kp  = dd.K;
    const u16* __restrict__ VTp = dd.VT;

    const int tid  = threadIdx.x;
    const int lane = tid & 63, w = tid >> 6;
    const int quad = lane >> 4, l16 = lane & 15;
    const int qhalf = w & 1, khalf = w >> 1;
    const int halfN = Nk >> 1;

    __shared__ u16 smem[13440];       // 26880 B
    u16* Ks = smem;                   // [64 rows][64]: row = khalfbit*32 + localkey
    u16* Vs = smem + 4096;            // [64 d][64 tile-keys], same XOR scheme
    u16* Pb = smem + 8192;            // 4 x [32 q][40]
    float* Lb = (float*)(smem + 13312);  // 64 floats

    bf16x8 aq[2][2];
#pragma unroll
    for (int ms = 0; ms < 2; ++ms)
#pragma unroll
        for (int kc = 0; kc < 2; ++kc) {
            int q = q0 + qhalf * 32 + ms * 16 + l16;
            aq[ms][kc] = *(const bf16x8*)(Qp + (size_t)q * D + h * 64 + kc * 32 + quad * 8);
        }

    f32x4 o[2][4];
#pragma unroll
    for (int ms = 0; ms < 2; ++ms)
#pragma unroll
        for (int nj = 0; nj < 4; ++nj) o[ms][nj] = (f32x4){0.f, 0.f, 0.f, 0.f};
    float rs[2][4] = {};
    const float sc = 0.125f;
    u16* P = Pb + w * 1280;
    const size_t vtBase = (size_t)h * 64 * Nk;

    const int row0 = tid >> 3, slot0 = tid & 7;          // chunk coords, j=0
    const int row1 = (tid + 256) >> 3, slot1 = tid & 7;  // j=1 (slot same)
    // prefetch tile 0
    u16x8 kr[2], vr[2];
    {
        int src0 = slot0 ^ (row0 & 7), src1 = slot1 ^ (row1 & 7);
        int gk0 = (row0 >> 5) * halfN + (row0 & 31);
        int gk1 = (row1 >> 5) * halfN + (row1 & 31);
        kr[0] = *(const u16x8*)(Kp + (size_t)gk0 * D + h * 64 + src0 * 8);
        kr[1] = *(const u16x8*)(Kp + (size_t)gk1 * D + h * 64 + src1 * 8);
        int gv0 = (src0 >> 2) * halfN + (src0 & 3) * 8;
        int gv1 = (src1 >> 2) * halfN + (src1 & 3) * 8;
        vr[0] = *(const u16x8*)(VTp + vtBase + (size_t)row0 * Nk + gv0);
        vr[1] = *(const u16x8*)(VTp + vtBase + (size_t)row1 * Nk + gv1);
    }

    for (int k0 = 0; k0 < halfN; k0 += 32) {
        __syncthreads();              // prev iter LDS reads done
        *(u16x8*)(Ks + row0 * 64 + slot0 * 8) = kr[0];
        *(u16x8*)(Ks + row1 * 64 + slot1 * 8) = kr[1];
        *(u16x8*)(Vs + row0 * 64 + slot0 * 8) = vr[0];
        *(u16x8*)(Vs + row1 * 64 + slot1 * 8) = vr[1];
        __syncthreads();              // staged

        // prefetch next tile (overlaps with compute below)
        {
            int kn = (k0 + 32 < halfN) ? (k0 + 32) : 0;
            int src0 = slot0 ^ (row0 & 7), src1 = slot1 ^ (row1 & 7);
            int gk0 = (row0 >> 5) * halfN + kn + (row0 & 31);
            int gk1 = (row1 >> 5) * halfN + kn + (row1 & 31);
            kr[0] = *(const u16x8*)(Kp + (size_t)gk0 * D + h * 64 + src0 * 8);
            kr[1] = *(const u16x8*)(Kp + (size_t)gk1 * D + h * 64 + src1 * 8);
            int gv0 = (src0 >> 2) * halfN + kn + (src0 & 3) * 8;
            int gv1 = (src1 >> 2) * halfN + kn + (src1 & 3) * 8;
            vr[0] = *(const u16x8*)(VTp + vtBase + (size_t)row0 * Nk + gv0);
            vr[1] = *(const u16x8*)(VTp + vtBase + (size_t)row1 * Nk + gv1);
        }

        // S = Q K^T over this wave's 32-key strip
        f32x4 s[2][2];
#pragma unroll
        for (int ms = 0; ms < 2; ++ms)
#pragma unroll
            for (int kn = 0; kn < 2; ++kn) s[ms][kn] = (f32x4){0.f, 0.f, 0.f, 0.f};
#pragma unroll
        for (int kn = 0; kn < 2; ++kn)
#pragma unroll
            for (int kc = 0; kc < 2; ++kc) {
                int keyr = khalf * 32 + kn * 16 + l16;
                int phys = ((kc * 4 + quad) ^ (keyr & 7)) * 8;
                bf16x8 bk = *(const bf16x8*)(Ks + keyr * 64 + phys);
#pragma unroll
                for (int ms = 0; ms < 2; ++ms)
                    s[ms][kn] = __builtin_amdgcn_mfma_f32_16x16x32_bf16(aq[ms][kc], bk, s[ms][kn], 0, 0, 0);
            }

        // exp + rowsum + P -> LDS
#pragma unroll
        for (int ms = 0; ms < 2; ++ms)
#pragma unroll
            for (int kn = 0; kn < 2; ++kn) {
                int key = kn * 16 + l16;
#pragma unroll
                for (int r = 0; r < 4; ++r) {
                    float p = __expf(s[ms][kn][r] * sc);
                    rs[ms][r] += p;
                    int ql = ms * 16 + quad * 4 + r;
                    P[ql * 40 + key] = f32_bf16(p);
                }
            }

        bf16x8 pa[2];
#pragma unroll
        for (int ms = 0; ms < 2; ++ms)
            pa[ms] = *(const bf16x8*)(P + (ms * 16 + l16) * 40 + quad * 8);

        // PV: V logical chunk = khalf*4 + quad, row d
#pragma unroll
        for (int nj = 0; nj < 4; ++nj) {
            int d = nj * 16 + l16;
            int physv = ((khalf * 4 + quad) ^ (d & 7)) * 8;
            bf16x8 bv = *(const bf16x8*)(Vs + d * 64 + physv);
#pragma unroll
            for (int ms = 0; ms < 2; ++ms)
                o[ms][nj] = __builtin_amdgcn_mfma_f32_16x16x32_bf16(pa[ms], bv, o[ms][nj], 0, 0, 0);
        }
    }

    // reduce row-sums across the 16 key-lanes
#pragma unroll
    for (int ms = 0; ms < 2; ++ms)
#pragma unroll
        for (int r = 0; r < 4; ++r) {
            float v = rs[ms][r];
            v += __shfl_xor(v, 1, 64);
            v += __shfl_xor(v, 2, 64);
            v += __shfl_xor(v, 4, 64);
            v += __shfl_xor(v, 8, 64);
            rs[ms][r] = v;
        }

    // cross-khalf combine (additive partials)
    __syncthreads();
    float* Cb = (float*)smem;         // [64 q][64 d] fp32 = 16 KB over Ks+Vs
    if (khalf == 1) {
#pragma unroll
        for (int ms = 0; ms < 2; ++ms)
#pragma unroll
            for (int nj = 0; nj < 4; ++nj)
#pragma unroll
                for (int r = 0; r < 4; ++r)
                    Cb[(qhalf * 32 + ms * 16 + quad * 4 + r) * 64 + nj * 16 + l16] = o[ms][nj][r];
        if (l16 == 0)
#pragma unroll
            for (int ms = 0; ms < 2; ++ms)
#pragma unroll
                for (int r = 0; r < 4; ++r)
                    Lb[qhalf * 32 + ms * 16 + quad * 4 + r] = rs[ms][r];
    }
    __syncthreads();
    if (khalf == 0) {
        float inv[2][4];
#pragma unroll
        for (int ms = 0; ms < 2; ++ms)
#pragma unroll
            for (int r = 0; r < 4; ++r)
                inv[ms][r] = 1.0f / (rs[ms][r] + Lb[qhalf * 32 + ms * 16 + quad * 4 + r]);

        u16* R = Pb + w * 2560;       // [64 d][40] u16
#pragma unroll
        for (int ms = 0; ms < 2; ++ms)
#pragma unroll
            for (int nj = 0; nj < 4; ++nj)
#pragma unroll
                for (int r = 0; r < 4; ++r) {
                    int d  = nj * 16 + l16;
                    int ql = ms * 16 + quad * 4 + r;
                    float v = o[ms][nj][r] + Cb[(qhalf * 32 + ql) * 64 + nj * 16 + l16];
                    R[d * 40 + ql] = f32_bf16(v * inv[ms][r]);
                }
#pragma unroll
        for (int i = 0; i < 4; ++i) {
            int cid = lane + 64 * i;
            int d = cid >> 2, c = cid & 3;
            u16x8 v = *(const u16x8*)(R + d * 40 + c * 8);
            *(u16x8*)(dd.ctxT + (size_t)h * 64 * Nq + (size_t)d * Nq + q0 + qhalf * 32 + c * 8) = v;
        }
    }
}

// ---------------------------------------------------------------------------
// launch — ws peak 40 MB (<= 44 proven by R2/R3). d_out u16 staging as R8.
// ---------------------------------------------------------------------------
extern "C" void kernel_launch(void* const* d_in, const int* in_sizes, int n_in,
                              void* d_out, int out_size, void* d_ws, size_t ws_size,
                              hipStream_t stream) {
    u16* ws = (u16*)d_ws;
    uint32_t* flag = (uint32_t*)ws;
    u16* A = ws + 64;
    const size_t M1 = 1024ull * 1024;

    u16* W8   = A;              // [0,8M)  : 8 weightsT; [0,3M) later ctx1
    u16* Kd1  = A + 8 * M1;     // [8M,10M) : X@WK natural
    u16* VT   = A + 10 * M1;    // [10M,12M): VT[16][64][2048]
    u16* K1d  = A + 12 * M1;    // [12M,15M): X1@WK1 natural
    u16* VT1  = A + 15 * M1;    // [15M,18M): VT1[16][64][3072]
    u16* ctx2 = A + 18 * M1;    // [18M,20M)

    u16* outw = (u16*)d_out;
    u16* Q1s  = outw;           // [0,3M)  X1@WQ1 (bf16 scratch in d_out)
    u16* Qs   = outw + 3 * M1;  // [3M,5M) X@WQ
    u16* Xb   = outw + 5 * M1;  // [5M,7M)  X as bf16
    u16* X1b  = outw + 7 * M1;  // [7M,10M) X1 as bf16

    u16* ctx1 = W8;             // over QKV weights (dead after projections)
    u16* WfcT = W8 + 6 * M1;    // Wfc/Wfc1 transposes survive until final GEMM

    // 0. dtype detect
    detect_k<<<dim3(1), dim3(256), 0, stream>>>((const u16*)d_in[0], flag);

    // 0b. X, X1 -> bf16
    XJob xj0 = {d_in[0], Xb,  2048 * 1024};
    XJob xj1 = {d_in[1], X1b, 3072 * 1024};
    convert_x<<<dim3(128, 2), dim3(256), 0, stream>>>(xj0, xj1, flag);

    // 1. transpose+convert all 8 weights in one dispatch
    WBatch8 wb;
    for (int i = 0; i < 8; ++i) { wb.j[i].in = d_in[2 + i]; wb.j[i].out = W8 + (size_t)i * M1; }
    convert_w<<<dim3(16, 16, 8), dim3(256), 0, stream>>>(wb, flag);

    // 2. all 6 projections in one dispatch
    GemmBatch6 gp;
    gp.j[0] = (GemmJob){Xb,  W8,          Qs,  2048, 0, 0, 0};
    gp.j[1] = (GemmJob){Xb,  W8 + M1,     Kd1, 2048, 0, 0, 0};
    gp.j[2] = (GemmJob){Xb,  W8 + 2 * M1, VT,  2048, 0, 0, 2048};
    gp.j[3] = (GemmJob){X1b, W8 + 3 * M1, Q1s, 3072, 0, 0, 0};
    gp.j[4] = (GemmJob){X1b, W8 + 4 * M1, K1d, 3072, 0, 0, 0};
    gp.j[5] = (GemmJob){X1b, W8 + 5 * M1, VT1, 3072, 0, 0, 3072};
    gemm_bt<<<dim3(8, 24, 6), dim3(256), 0, stream>>>(gp, flag);

    // 3. fused attention, both directions
    AttnDir a0 = {Q1s, Kd1, VT,  ctx1, 3072, 2048, 768};
    AttnDir a1 = {Qs,  K1d, VT1, ctx2, 2048, 3072, 512};
    attn_k<<<dim3(1280), dim3(256), 0, stream>>>(a0, a1);

    // 4. output GEMMs into d_out (fp32 when flag; d_out staging dead)
    GemmBatch6 gf;
    gf.j[0] = (GemmJob){ctx1, WfcT,      d_out, 3072, 1, 0,               0};
    gf.j[1] = (GemmJob){ctx2, WfcT + M1, d_out, 2048, 1, 3 * 1024 * 1024, 0};
    gf.j[2] = gf.j[0]; gf.j[3] = gf.j[0]; gf.j[4] = gf.j[0]; gf.j[5] = gf.j[0];
    gemm_bt<<<dim3(8, 24, 2), dim3(256), 0, stream>>>(gf, flag);
}